// Round 10
// baseline (258.055 us; speedup 1.0000x reference)
//
#include <hip/hip_runtime.h>
#include <cstddef>

// Problem constants (fixed by the reference)
#define EPQ_SHIFT 11       // EPQ = 2048
#define KSEL 256

typedef __attribute__((ext_vector_type(8))) short short8v;   // 8 bf16
typedef __attribute__((ext_vector_type(4))) float float4v;   // MFMA acc

__device__ __forceinline__ unsigned enc_f(float f) {
  unsigned u = __float_as_uint(f);
  return (u & 0x80000000u) ? ~u : (u | 0x80000000u);
}
__device__ __forceinline__ float dec_f(unsigned k) {
  unsigned u = (k & 0x80000000u) ? (k ^ 0x80000000u) : ~k;
  return __uint_as_float(u);
}
__device__ __forceinline__ unsigned short f2bf(float x) {  // RNE f32->bf16
  unsigned u = __float_as_uint(x);
  return (unsigned short)((u + 0x7FFFu + ((u >> 16) & 1u)) >> 16);
}

// ---------------- K0: init output + segment buffers ----------------
__global__ void k0_init(float* __restrict__ out, float* __restrict__ segsum,
                        unsigned* __restrict__ segkey, int n) {
  int i = blockIdx.x * 256 + threadIdx.x;
  if (i < n) { out[i] = 0.f; segsum[i] = 0.f; segkey[i] = 0u; }
}

// ---------------- K1: M = Wq^T Wk (512x512), Mt, + bf16 hi/lo splits ------
__global__ __launch_bounds__(256) void k1_gemmM(
    const float* __restrict__ Wq, const float* __restrict__ Wk,
    float* __restrict__ M, float* __restrict__ Mt,
    unsigned short* __restrict__ Mh, unsigned short* __restrict__ Ml,
    unsigned short* __restrict__ Mth, unsigned short* __restrict__ Mtl) {
  __shared__ float as[16][64];
  __shared__ float bs[16][64];
  int tid = threadIdx.x;
  int tx = tid & 15, ty = tid >> 4;
  int c1b = blockIdx.y * 64, c2b = blockIdx.x * 64;
  float acc[4][4] = {};
  for (int k0 = 0; k0 < 512; k0 += 16) {
#pragma unroll
    for (int l = 0; l < 4; ++l) {
      int lin = tid + l * 256;
      int kk = lin >> 6, c = lin & 63;
      as[kk][c] = Wq[(k0 + kk) * 512 + c1b + c];
      bs[kk][c] = Wk[(k0 + kk) * 512 + c2b + c];
    }
    __syncthreads();
#pragma unroll
    for (int kk = 0; kk < 16; ++kk) {
      float a[4], b[4];
#pragma unroll
      for (int m = 0; m < 4; ++m) a[m] = as[kk][ty * 4 + m];
#pragma unroll
      for (int n = 0; n < 4; ++n) b[n] = bs[kk][tx * 4 + n];
#pragma unroll
      for (int m = 0; m < 4; ++m)
#pragma unroll
        for (int n = 0; n < 4; ++n) acc[m][n] += a[m] * b[n];
    }
    __syncthreads();
  }
#pragma unroll
  for (int m = 0; m < 4; ++m)
#pragma unroll
    for (int n = 0; n < 4; ++n) {
      int c1 = c1b + ty * 4 + m, c2 = c2b + tx * 4 + n;
      float v = acc[m][n];
      M[c1 * 512 + c2] = v;
      Mt[c2 * 512 + c1] = v;
      unsigned short h = f2bf(v);
      unsigned short lo = f2bf(v - __uint_as_float((unsigned)h << 16));
      Mh[c1 * 512 + c2] = h;
      Ml[c1 * 512 + c2] = lo;
      Mth[c2 * 512 + c1] = h;
      Mtl[c2 * 512 + c1] = lo;
    }
}

// ===== MFMA micro-kernel (split-bf16, 3 products) =====
// Block 256 thr = 4 waves; tile 128 rows x 128 cols; wave w -> quadrant
// (wr2=w>>1 rows, wc2=w&1 cols), 4x4 frags of 16x16, K-chunks of 32.
// LDS tiles [128][32] bf16 (hi,lo for A and B), 16B-group swizzle
// g' = g ^ ((row>>1)&3) -> uniform 8-way b128 frag reads.
#define STAGE_A_F32(SRC_PTR)                                                 \
  {                                                                          \
    const float* s = (SRC_PTR);                                              \
    float4 v0 = *(const float4*)&s[0];                                       \
    float4 v1 = *(const float4*)&s[4];                                       \
    float4 v2 = *(const float4*)&s[8];                                       \
    float4 v3 = *(const float4*)&s[12];                                      \
    float vv[16] = {v0.x, v0.y, v0.z, v0.w, v1.x, v1.y, v1.z, v1.w,          \
                    v2.x, v2.y, v2.z, v2.w, v3.x, v3.y, v3.z, v3.w};         \
    unsigned hw[8], lw[8];                                                   \
    _Pragma("unroll") for (int j = 0; j < 8; ++j) {                          \
      unsigned short h0 = f2bf(vv[2 * j]);                                   \
      unsigned short h1 = f2bf(vv[2 * j + 1]);                               \
      unsigned short l0 =                                                    \
          f2bf(vv[2 * j] - __uint_as_float((unsigned)h0 << 16));             \
      unsigned short l1 =                                                    \
          f2bf(vv[2 * j + 1] - __uint_as_float((unsigned)h1 << 16));         \
      hw[j] = (unsigned)h0 | ((unsigned)h1 << 16);                           \
      lw[j] = (unsigned)l0 | ((unsigned)l1 << 16);                           \
    }                                                                        \
    int sw = (sn >> 1) & 3;                                                  \
    int g0 = (shalf * 2) ^ sw, g1 = (shalf * 2 + 1) ^ sw;                    \
    *(uint4*)&Ah[sn][g0 * 8] = make_uint4(hw[0], hw[1], hw[2], hw[3]);       \
    *(uint4*)&Ah[sn][g1 * 8] = make_uint4(hw[4], hw[5], hw[6], hw[7]);       \
    *(uint4*)&Al[sn][g0 * 8] = make_uint4(lw[0], lw[1], lw[2], lw[3]);       \
    *(uint4*)&Al[sn][g1 * 8] = make_uint4(lw[4], lw[5], lw[6], lw[7]);       \
  }

#define STAGE_B_BF16(HSRC, LSRC)                                             \
  {                                                                          \
    const unsigned short* sh_ = (HSRC);                                      \
    const unsigned short* sl_ = (LSRC);                                      \
    uint4 q0 = *(const uint4*)&sh_[0];                                       \
    uint4 q1 = *(const uint4*)&sh_[8];                                       \
    uint4 p0 = *(const uint4*)&sl_[0];                                       \
    uint4 p1 = *(const uint4*)&sl_[8];                                       \
    int sw = (sn >> 1) & 3;                                                  \
    int g0 = (shalf * 2) ^ sw, g1 = (shalf * 2 + 1) ^ sw;                    \
    *(uint4*)&Bh[sn][g0 * 8] = q0;                                           \
    *(uint4*)&Bh[sn][g1 * 8] = q1;                                           \
    *(uint4*)&Bl[sn][g0 * 8] = p0;                                           \
    *(uint4*)&Bl[sn][g1 * 8] = p1;                                           \
  }

#define MFMA_CHUNK()                                                         \
  {                                                                          \
    int ln = lane & 15, kq = lane >> 4;                                      \
    short8v ah[4], al[4];                                                    \
    _Pragma("unroll") for (int r = 0; r < 4; ++r) {                          \
      int row = wr2 * 64 + r * 16 + ln;                                      \
      int gg = kq ^ ((row >> 1) & 3);                                        \
      ah[r] = *(const short8v*)&Ah[row][gg * 8];                             \
      al[r] = *(const short8v*)&Al[row][gg * 8];                             \
    }                                                                        \
    _Pragma("unroll") for (int c = 0; c < 4; ++c) {                          \
      int col = wc2 * 64 + c * 16 + ln;                                      \
      int gg = kq ^ ((col >> 1) & 3);                                        \
      short8v bh = *(const short8v*)&Bh[col][gg * 8];                        \
      short8v bl = *(const short8v*)&Bl[col][gg * 8];                        \
      _Pragma("unroll") for (int r = 0; r < 4; ++r) {                        \
        acc[r][c] = __builtin_amdgcn_mfma_f32_16x16x32_bf16(                 \
            ah[r], bh, acc[r][c], 0, 0, 0);                                  \
        acc[r][c] = __builtin_amdgcn_mfma_f32_16x16x32_bf16(                 \
            ah[r], bl, acc[r][c], 0, 0, 0);                                  \
        acc[r][c] = __builtin_amdgcn_mfma_f32_16x16x32_bf16(                 \
            al[r], bh, acc[r][c], 0, 0, 0);                                  \
      }                                                                      \
    }                                                                        \
  }

// ---------------- K2m: node projections J0/J1/I1 via MFMA (fp32 out) ------
__global__ __launch_bounds__(256) void k2m_mfma(
    const float* __restrict__ hv, const unsigned short* __restrict__ Mh,
    const unsigned short* __restrict__ Ml, const unsigned short* __restrict__ Mth,
    const unsigned short* __restrict__ Mtl, float* __restrict__ J0,
    float* __restrict__ J1, float* __restrict__ I1, int N) {
  __shared__ char pool[32768];
  unsigned short (*Ah)[32] = (unsigned short(*)[32])pool;
  unsigned short (*Al)[32] = (unsigned short(*)[32])(pool + 8192);
  unsigned short (*Bh)[32] = (unsigned short(*)[32])(pool + 16384);
  unsigned short (*Bl)[32] = (unsigned short(*)[32])(pool + 24576);
  float (*ep)[34] = (float(*)[34])pool;

  const int tid = threadIdx.x;
  const int lane = tid & 63;
  const int w = tid >> 6;
  const int wr2 = w >> 1, wc2 = w & 1;
  const int p = blockIdx.x;
  const int n0 = blockIdx.y * 128;
  const unsigned short* bhs = (p == 2) ? Mth : Mh;
  const unsigned short* bls = (p == 2) ? Mtl : Ml;
  const int rowoff = (p == 0) ? 0 : 128;
  float* outp = (p == 0) ? J0 : (p == 1) ? J1 : I1;

  float4v acc[4][4];
#pragma unroll
  for (int r = 0; r < 4; ++r)
#pragma unroll
    for (int c = 0; c < 4; ++c) acc[r][c] = (float4v){0.f, 0.f, 0.f, 0.f};

  const int sn = tid >> 1, shalf = tid & 1;
  for (int ch = 0; ch < 4; ++ch) {
    __syncthreads();
    {
      int gn = n0 + sn;
      gn = gn < N ? gn : N - 1;
      STAGE_A_F32(hv + (size_t)gn * 128 + ch * 32 + shalf * 16);
      size_t boff = (size_t)(rowoff + sn) * 512 + ch * 32 + shalf * 16;
      STAGE_B_BF16(bhs + boff, bls + boff);
    }
    __syncthreads();
    MFMA_CHUNK();
  }

  // epilogue: per 32-col group, transpose via LDS, coalesced fp32 store
  for (int g = 0; g < 4; ++g) {
    __syncthreads();
    if (wc2 == (g >> 1)) {
      int ln = lane & 15, kq = lane >> 4;
#pragma unroll
      for (int cc = 0; cc < 2; ++cc) {
        int c = (g & 1) * 2 + cc;
#pragma unroll
        for (int r = 0; r < 4; ++r)
#pragma unroll
          for (int reg = 0; reg < 4; ++reg)
            ep[wr2 * 64 + r * 16 + kq * 4 + reg][cc * 16 + ln] = acc[r][c][reg];
      }
    }
    __syncthreads();
    int row = tid >> 1, half = tid & 1;
    int gn = n0 + row;
    if (gn < N) {
#pragma unroll
      for (int j = 0; j < 4; ++j)
        *(float4*)&outp[(size_t)gn * 128 + 32 * g + 16 * half + 4 * j] =
            *(const float4*)&ep[row][16 * half + 4 * j];
    }
  }
}

// ---------------- K3: per-query vectors w,u,y and scalar c_b ----------------
__global__ __launch_bounds__(128) void k3_query(const float* __restrict__ qsrc,
                                                const float* __restrict__ qrel,
                                                const float* __restrict__ M,
                                                const float* __restrict__ Mt,
                                                float* __restrict__ wv,
                                                float* __restrict__ uv,
                                                float* __restrict__ yv,
                                                float* __restrict__ cb) {
  __shared__ float qcat[256];
  __shared__ float red[128];
  int b = blockIdx.x, d = threadIdx.x;
  qcat[d] = qsrc[b * 128 + d];
  qcat[128 + d] = qrel[b * 128 + d];
  __syncthreads();
  float w = 0.f, u = 0.f, y = 0.f, t1 = 0.f, t2 = 0.f;
  for (int c = 0; c < 256; ++c) {
    float q = qcat[c];
    size_t row = (size_t)(256 + c) * 512;
    w += Mt[row + d] * q;                        // M[d][256+c]
    u += M[row + d] * q;                         // M[256+c][d]
    y += (Mt[row + 128 + d] + M[row + 128 + d]) * q;  // x + v
    t1 += M[row + 256 + d] * q;                  // for c_b, col 256+d
    t2 += M[row + 384 + d] * q;                  // for c_b, col 384+d
  }
  wv[b * 128 + d] = w;
  uv[b * 128 + d] = u;
  yv[b * 128 + d] = y;
  red[d] = qcat[d] * t1 + qcat[128 + d] * t2;
  __syncthreads();
  for (int s = 64; s > 0; s >>= 1) {
    if (d < s) red[d] += red[d + s];
    __syncthreads();
  }
  if (d == 0) cb[b] = red[0];
}

// ---------------- K4m: edge_const via MFMA ----------------
__global__ __launch_bounds__(256) void k4m_mfma(
    const float* __restrict__ rel, const unsigned short* __restrict__ Mth,
    const unsigned short* __restrict__ Mtl, const float* __restrict__ yv,
    const float* __restrict__ cbp, float* __restrict__ ec) {
  __shared__ char pool[32768];
  unsigned short (*Ah)[32] = (unsigned short(*)[32])pool;
  unsigned short (*Al)[32] = (unsigned short(*)[32])(pool + 8192);
  unsigned short (*Bh)[32] = (unsigned short(*)[32])(pool + 16384);
  unsigned short (*Bl)[32] = (unsigned short(*)[32])(pool + 24576);
  float (*ep)[34] = (float(*)[34])pool;

  const int tid = threadIdx.x;
  const int lane = tid & 63;
  const int w = tid >> 6;
  const int wr2 = w >> 1, wc2 = w & 1;
  const int e0 = blockIdx.x * 128;
  const int b = e0 >> EPQ_SHIFT;

  float4v acc[4][4];
#pragma unroll
  for (int r = 0; r < 4; ++r)
#pragma unroll
    for (int c = 0; c < 4; ++c) acc[r][c] = (float4v){0.f, 0.f, 0.f, 0.f};

  const int sn = tid >> 1, shalf = tid & 1;
  for (int ch = 0; ch < 4; ++ch) {
    __syncthreads();
    {
      STAGE_A_F32(rel + (size_t)(e0 + sn) * 128 + ch * 32 + shalf * 16);
      size_t boff = (size_t)(128 + sn) * 512 + 128 + ch * 32 + shalf * 16;
      STAGE_B_BF16(Mth + boff, Mtl + boff);
    }
    __syncthreads();
    MFMA_CHUNK();
  }

  float part = 0.f;
  const int e_loc = tid >> 1, half = tid & 1;
  for (int g = 0; g < 4; ++g) {
    __syncthreads();
    if (wc2 == (g >> 1)) {
      int ln = lane & 15, kq = lane >> 4;
#pragma unroll
      for (int cc = 0; cc < 2; ++cc) {
        int c = (g & 1) * 2 + cc;
#pragma unroll
        for (int r = 0; r < 4; ++r)
#pragma unroll
          for (int reg = 0; reg < 4; ++reg)
            ep[wr2 * 64 + r * 16 + kq * 4 + reg][cc * 16 + ln] = acc[r][c][reg];
      }
    }
    __syncthreads();
    const float* rsrc = rel + (size_t)(e0 + e_loc) * 128 + 32 * g + 16 * half;
    const float* ysrc = yv + b * 128 + 32 * g + 16 * half;
#pragma unroll
    for (int j = 0; j < 4; ++j) {
      float4 q = *(const float4*)&ep[e_loc][16 * half + 4 * j];
      float4 rr = *(const float4*)&rsrc[4 * j];
      float4 yy = *(const float4*)&ysrc[4 * j];
      part += (q.x + yy.x) * rr.x + (q.y + yy.y) * rr.y +
              (q.z + yy.z) * rr.z + (q.w + yy.w) * rr.w;
    }
  }
  part += __shfl_xor(part, 1, 64);
  if ((tid & 1) == 0) ec[e0 + e_loc] = part + cbp[b];
}

// ---------------- K5: per-edge logits + segment max (fp32, 64 edges/blk) ---
__global__ __launch_bounds__(256) void k5_logits(const float* __restrict__ rel,
                                                 const float* __restrict__ hv,
                                                 const float* __restrict__ J0,
                                                 const float* __restrict__ J1,
                                                 const float* __restrict__ I1,
                                                 const float* __restrict__ wv,
                                                 const float* __restrict__ uv,
                                                 const float* __restrict__ ec,
                                                 const int* __restrict__ node_i,
                                                 const int* __restrict__ node_j,
                                                 float* __restrict__ logits,
                                                 unsigned* __restrict__ segkey) {
  __shared__ float wl[128];
  __shared__ float ul[128];
  int tid = threadIdx.x;
  int e0 = blockIdx.x * 64;
  int b = e0 >> EPQ_SHIFT;
  if (tid < 128) wl[tid] = wv[b * 128 + tid];
  else ul[tid - 128] = uv[b * 128 + (tid - 128)];
  __syncthreads();
  int lane = tid & 15, eg = tid >> 4;
  int c0 = lane * 8;

  for (int s = 0; s < 4; ++s) {
    int e = e0 + s * 16 + eg;
    int i = node_i[e], j = node_j[e];

    float rr[8], hi[8], hj[8], a0[8], a1[8], ii[8];
    *(float4*)&rr[0] = *(const float4*)&rel[(size_t)e * 128 + c0];
    *(float4*)&rr[4] = *(const float4*)&rel[(size_t)e * 128 + c0 + 4];
    *(float4*)&hi[0] = *(const float4*)&hv[(size_t)i * 128 + c0];
    *(float4*)&hi[4] = *(const float4*)&hv[(size_t)i * 128 + c0 + 4];
    *(float4*)&hj[0] = *(const float4*)&hv[(size_t)j * 128 + c0];
    *(float4*)&hj[4] = *(const float4*)&hv[(size_t)j * 128 + c0 + 4];
    *(float4*)&a0[0] = *(const float4*)&J0[(size_t)j * 128 + c0];
    *(float4*)&a0[4] = *(const float4*)&J0[(size_t)j * 128 + c0 + 4];
    *(float4*)&a1[0] = *(const float4*)&J1[(size_t)j * 128 + c0];
    *(float4*)&a1[4] = *(const float4*)&J1[(size_t)j * 128 + c0 + 4];
    *(float4*)&ii[0] = *(const float4*)&I1[(size_t)i * 128 + c0];
    *(float4*)&ii[4] = *(const float4*)&I1[(size_t)i * 128 + c0 + 4];

    float p = 0.f;
#pragma unroll
    for (int k = 0; k < 8; ++k) {
      p += hi[k] * a0[k];               // hvi . J0[j]
      p += rr[k] * (a1[k] + ii[k]);     // rel . (J1[j] + I1[i])
      p += hi[k] * wl[c0 + k];          // hvi . w_b
      p += hj[k] * ul[c0 + k];          // hvj . u_b
    }
#pragma unroll
    for (int m = 8; m >= 1; m >>= 1) p += __shfl_xor(p, m, 64);
    if (lane == 0) {
      float lg = p + ec[e];
      logits[e] = lg;
      atomicMax(&segkey[i], enc_f(lg));
    }
  }
}

// ---------------- K6: ex = exp(logit - segmax), segment sum ----------------
__global__ void k6_exp(float* __restrict__ exb, const int* __restrict__ node_i,
                       const unsigned* __restrict__ segkey,
                       float* __restrict__ segsum, int E) {
  int e = blockIdx.x * 256 + threadIdx.x;
  if (e >= E) return;
  int i = node_i[e];
  float m = dec_f(segkey[i]);
  float ex = expf(exb[e] - m);
  exb[e] = ex;
  atomicAdd(&segsum[i], ex);
}

// ---------------- K7: per-query exact top-256 radix select + scatter-add ----
__global__ __launch_bounds__(256) void k7_topk(const float* __restrict__ exb,
                                               const int* __restrict__ node_i,
                                               const int* __restrict__ node_j,
                                               const float* __restrict__ segsum,
                                               const float* __restrict__ score,
                                               float* __restrict__ out) {
  __shared__ unsigned vals[2048];
  __shared__ unsigned hist[256];
  __shared__ unsigned sc[256];
  __shared__ unsigned tie_scan[256];
  __shared__ unsigned sel_info[2];
  int q = blockIdx.x, t = threadIdx.x;
  size_t base = (size_t)q * 2048;
#pragma unroll
  for (int l = 0; l < 8; ++l) {
    int el = t * 8 + l;
    int i = node_i[base + el];
    float tgt = exb[base + el] / segsum[i] * score[i];  // attn * src_score >= 0
    vals[el] = __float_as_uint(tgt);
  }
  __syncthreads();
  unsigned prefix = 0, need = KSEL;
  for (int pass = 3; pass >= 0; --pass) {
    hist[t] = 0;
    __syncthreads();
    int sh = pass * 8;
#pragma unroll
    for (int l = 0; l < 8; ++l) {
      unsigned v = vals[t * 8 + l];
      bool match = (pass == 3) || ((v >> (sh + 8)) == (prefix >> (sh + 8)));
      if (match) atomicAdd(&hist[(v >> sh) & 255u], 1u);
    }
    __syncthreads();
    sc[t] = hist[t];
    __syncthreads();
    for (int off = 1; off < 256; off <<= 1) {  // suffix-inclusive sum
      unsigned add = (t + off < 256) ? sc[t + off] : 0u;
      __syncthreads();
      sc[t] += add;
      __syncthreads();
    }
    unsigned above = sc[t] - hist[t];
    if (above < need && need <= sc[t]) {
      sel_info[0] = (unsigned)t;
      sel_info[1] = need - above;
    }
    __syncthreads();
    prefix |= sel_info[0] << sh;
    need = sel_info[1];
    __syncthreads();
  }
  unsigned T = prefix, r = need;
  unsigned lc = 0;
#pragma unroll
  for (int l = 0; l < 8; ++l)
    if (vals[t * 8 + l] == T) lc++;
  tie_scan[t] = lc;
  __syncthreads();
  unsigned own = lc;
  for (int off = 1; off < 256; off <<= 1) {
    unsigned add = (t >= off) ? tie_scan[t - off] : 0u;
    __syncthreads();
    tie_scan[t] += add;
    __syncthreads();
  }
  unsigned excl = tie_scan[t] - own;
  unsigned cnt = 0;
#pragma unroll
  for (int l = 0; l < 8; ++l) {
    int el = t * 8 + l;
    unsigned v = vals[el];
    bool take = false;
    if (v > T) take = true;
    else if (v == T) { if (excl + cnt < r) take = true; cnt++; }
    if (take) {
      int j = node_j[base + el];
      atomicAdd(&out[j], __uint_as_float(v));
    }
  }
}

// ---------------- host ----------------
extern "C" void kernel_launch(void* const* d_in, const int* in_sizes, int n_in,
                              void* d_out, int out_size, void* d_ws, size_t ws_size,
                              hipStream_t stream) {
  const float* score = (const float*)d_in[0];
  const float* hv    = (const float*)d_in[1];
  const float* rel   = (const float*)d_in[2];
  const float* qsrc  = (const float*)d_in[3];
  const float* qrel  = (const float*)d_in[4];
  const float* Wq    = (const float*)d_in[5];
  const float* Wk    = (const float*)d_in[6];
  const int* node_i  = (const int*)d_in[8];
  const int* node_j  = (const int*)d_in[9];

  const int N = in_sizes[0];            // 50000
  const int B = in_sizes[3] / 128;      // 64
  const int E = in_sizes[2] / 128;      // 131072

  float* ws = (float*)d_ws;
  float* M  = ws;
  float* Mt = M + 262144;
  float* J0 = Mt + 262144;
  float* J1 = J0 + (size_t)N * 128;
  float* I1 = J1 + (size_t)N * 128;
  float* wv = I1 + (size_t)N * 128;
  float* uv = wv + (size_t)B * 128;
  float* yv = uv + (size_t)B * 128;
  float* cb = yv + (size_t)B * 128;
  float* ec = cb + B;
  float* exb = ec + E;
  unsigned* segkey = (unsigned*)(exb + E);
  float* segsum = (float*)(segkey + N);
  unsigned short* Mh  = (unsigned short*)(segsum + N);
  unsigned short* Ml  = Mh + 262144;
  unsigned short* Mth = Ml + 262144;
  unsigned short* Mtl = Mth + 262144;
  float* out = (float*)d_out;

  k0_init<<<(N + 255) / 256, 256, 0, stream>>>(out, segsum, segkey, N);
  k1_gemmM<<<dim3(8, 8), 256, 0, stream>>>(Wq, Wk, M, Mt, Mh, Ml, Mth, Mtl);
  k2m_mfma<<<dim3(3, (N + 127) / 128), 256, 0, stream>>>(hv, Mh, Ml, Mth, Mtl,
                                                         J0, J1, I1, N);
  k3_query<<<B, 128, 0, stream>>>(qsrc, qrel, M, Mt, wv, uv, yv, cb);
  k4m_mfma<<<E / 128, 256, 0, stream>>>(rel, Mth, Mtl, yv, cb, ec);
  k5_logits<<<E / 64, 256, 0, stream>>>(rel, hv, J0, J1, I1, wv, uv, ec,
                                        node_i, node_j, exb, segkey);
  k6_exp<<<(E + 255) / 256, 256, 0, stream>>>(exb, node_i, segkey, segsum, E);
  k7_topk<<<B, 256, 0, stream>>>(exb, node_i, node_j, segsum, score, out);
}

// Round 11
// 228.095 us; speedup vs baseline: 1.1313x; 1.1313x over previous
//
#include <hip/hip_runtime.h>
#include <cstddef>

// Problem constants (fixed by the reference)
#define EPQ_SHIFT 11       // EPQ = 2048
#define KSEL 256

typedef __attribute__((ext_vector_type(8))) short short8v;   // 8 bf16
typedef __attribute__((ext_vector_type(4))) float float4v;   // MFMA acc

__device__ __forceinline__ unsigned enc_f(float f) {
  unsigned u = __float_as_uint(f);
  return (u & 0x80000000u) ? ~u : (u | 0x80000000u);
}
__device__ __forceinline__ float dec_f(unsigned k) {
  unsigned u = (k & 0x80000000u) ? (k ^ 0x80000000u) : ~k;
  return __uint_as_float(u);
}
__device__ __forceinline__ unsigned short f2bf(float x) {  // RNE f32->bf16
  unsigned u = __float_as_uint(x);
  return (unsigned short)((u + 0x7FFFu + ((u >> 16) & 1u)) >> 16);
}

// ---------------- K0: init output + segment buffers ----------------
__global__ void k0_init(float* __restrict__ out, float* __restrict__ segsum,
                        unsigned* __restrict__ segkey, int n) {
  int i = blockIdx.x * 256 + threadIdx.x;
  if (i < n) { out[i] = 0.f; segsum[i] = 0.f; segkey[i] = 0u; }
}

// ---------------- K1: M = Wq^T Wk (512x512), Mt, + bf16 hi/lo splits ------
__global__ __launch_bounds__(256) void k1_gemmM(
    const float* __restrict__ Wq, const float* __restrict__ Wk,
    float* __restrict__ M, float* __restrict__ Mt,
    unsigned short* __restrict__ Mh, unsigned short* __restrict__ Ml,
    unsigned short* __restrict__ Mth, unsigned short* __restrict__ Mtl) {
  __shared__ float as[16][64];
  __shared__ float bs[16][64];
  int tid = threadIdx.x;
  int tx = tid & 15, ty = tid >> 4;
  int c1b = blockIdx.y * 64, c2b = blockIdx.x * 64;
  float acc[4][4] = {};
  for (int k0 = 0; k0 < 512; k0 += 16) {
#pragma unroll
    for (int l = 0; l < 4; ++l) {
      int lin = tid + l * 256;
      int kk = lin >> 6, c = lin & 63;
      as[kk][c] = Wq[(k0 + kk) * 512 + c1b + c];
      bs[kk][c] = Wk[(k0 + kk) * 512 + c2b + c];
    }
    __syncthreads();
#pragma unroll
    for (int kk = 0; kk < 16; ++kk) {
      float a[4], b[4];
#pragma unroll
      for (int m = 0; m < 4; ++m) a[m] = as[kk][ty * 4 + m];
#pragma unroll
      for (int n = 0; n < 4; ++n) b[n] = bs[kk][tx * 4 + n];
#pragma unroll
      for (int m = 0; m < 4; ++m)
#pragma unroll
        for (int n = 0; n < 4; ++n) acc[m][n] += a[m] * b[n];
    }
    __syncthreads();
  }
#pragma unroll
  for (int m = 0; m < 4; ++m)
#pragma unroll
    for (int n = 0; n < 4; ++n) {
      int c1 = c1b + ty * 4 + m, c2 = c2b + tx * 4 + n;
      float v = acc[m][n];
      M[c1 * 512 + c2] = v;
      Mt[c2 * 512 + c1] = v;
      unsigned short h = f2bf(v);
      unsigned short lo = f2bf(v - __uint_as_float((unsigned)h << 16));
      Mh[c1 * 512 + c2] = h;
      Ml[c1 * 512 + c2] = lo;
      Mth[c2 * 512 + c1] = h;
      Mtl[c2 * 512 + c1] = lo;
    }
}

// ===== MFMA micro-kernel (split-bf16, 3 products) =====
// Block 256 thr = 4 waves; tile 128 rows x 128 cols; wave w -> quadrant
// (wr2=w>>1 rows, wc2=w&1 cols), 4x4 frags of 16x16, K-chunks of 32.
// LDS tiles [128][32] bf16 (hi,lo for A and B), 16B-group swizzle
// g' = g ^ ((row>>1)&3) -> uniform 8-way b128 frag reads.
#define STAGE_A_F32(SRC_PTR)                                                 \
  {                                                                          \
    const float* s = (SRC_PTR);                                              \
    float4 v0 = *(const float4*)&s[0];                                       \
    float4 v1 = *(const float4*)&s[4];                                       \
    float4 v2 = *(const float4*)&s[8];                                       \
    float4 v3 = *(const float4*)&s[12];                                      \
    float vv[16] = {v0.x, v0.y, v0.z, v0.w, v1.x, v1.y, v1.z, v1.w,          \
                    v2.x, v2.y, v2.z, v2.w, v3.x, v3.y, v3.z, v3.w};         \
    unsigned hw[8], lw[8];                                                   \
    _Pragma("unroll") for (int j = 0; j < 8; ++j) {                          \
      unsigned short h0 = f2bf(vv[2 * j]);                                   \
      unsigned short h1 = f2bf(vv[2 * j + 1]);                               \
      unsigned short l0 =                                                    \
          f2bf(vv[2 * j] - __uint_as_float((unsigned)h0 << 16));             \
      unsigned short l1 =                                                    \
          f2bf(vv[2 * j + 1] - __uint_as_float((unsigned)h1 << 16));         \
      hw[j] = (unsigned)h0 | ((unsigned)h1 << 16);                           \
      lw[j] = (unsigned)l0 | ((unsigned)l1 << 16);                           \
    }                                                                        \
    int sw = (sn >> 1) & 3;                                                  \
    int g0 = (shalf * 2) ^ sw, g1 = (shalf * 2 + 1) ^ sw;                    \
    *(uint4*)&Ah[sn][g0 * 8] = make_uint4(hw[0], hw[1], hw[2], hw[3]);       \
    *(uint4*)&Ah[sn][g1 * 8] = make_uint4(hw[4], hw[5], hw[6], hw[7]);       \
    *(uint4*)&Al[sn][g0 * 8] = make_uint4(lw[0], lw[1], lw[2], lw[3]);       \
    *(uint4*)&Al[sn][g1 * 8] = make_uint4(lw[4], lw[5], lw[6], lw[7]);       \
  }

#define STAGE_B_BF16(HSRC, LSRC)                                             \
  {                                                                          \
    const unsigned short* sh_ = (HSRC);                                      \
    const unsigned short* sl_ = (LSRC);                                      \
    uint4 q0 = *(const uint4*)&sh_[0];                                       \
    uint4 q1 = *(const uint4*)&sh_[8];                                       \
    uint4 p0 = *(const uint4*)&sl_[0];                                       \
    uint4 p1 = *(const uint4*)&sl_[8];                                       \
    int sw = (sn >> 1) & 3;                                                  \
    int g0 = (shalf * 2) ^ sw, g1 = (shalf * 2 + 1) ^ sw;                    \
    *(uint4*)&Bh[sn][g0 * 8] = q0;                                           \
    *(uint4*)&Bh[sn][g1 * 8] = q1;                                           \
    *(uint4*)&Bl[sn][g0 * 8] = p0;                                           \
    *(uint4*)&Bl[sn][g1 * 8] = p1;                                           \
  }

#define MFMA_CHUNK()                                                         \
  {                                                                          \
    int ln = lane & 15, kq = lane >> 4;                                      \
    short8v ah[4], al[4];                                                    \
    _Pragma("unroll") for (int r = 0; r < 4; ++r) {                          \
      int row = wr2 * 64 + r * 16 + ln;                                      \
      int gg = kq ^ ((row >> 1) & 3);                                        \
      ah[r] = *(const short8v*)&Ah[row][gg * 8];                             \
      al[r] = *(const short8v*)&Al[row][gg * 8];                             \
    }                                                                        \
    _Pragma("unroll") for (int c = 0; c < 4; ++c) {                          \
      int col = wc2 * 64 + c * 16 + ln;                                      \
      int gg = kq ^ ((col >> 1) & 3);                                        \
      short8v bh = *(const short8v*)&Bh[col][gg * 8];                        \
      short8v bl = *(const short8v*)&Bl[col][gg * 8];                        \
      _Pragma("unroll") for (int r = 0; r < 4; ++r) {                        \
        acc[r][c] = __builtin_amdgcn_mfma_f32_16x16x32_bf16(                 \
            ah[r], bh, acc[r][c], 0, 0, 0);                                  \
        acc[r][c] = __builtin_amdgcn_mfma_f32_16x16x32_bf16(                 \
            ah[r], bl, acc[r][c], 0, 0, 0);                                  \
        acc[r][c] = __builtin_amdgcn_mfma_f32_16x16x32_bf16(                 \
            al[r], bh, acc[r][c], 0, 0, 0);                                  \
      }                                                                      \
    }                                                                        \
  }

// ---------------- K2m: node projections J0/J1/I1 via MFMA (fp32 out) ------
__global__ __launch_bounds__(256) void k2m_mfma(
    const float* __restrict__ hv, const unsigned short* __restrict__ Mh,
    const unsigned short* __restrict__ Ml, const unsigned short* __restrict__ Mth,
    const unsigned short* __restrict__ Mtl, float* __restrict__ J0,
    float* __restrict__ J1, float* __restrict__ I1, int N) {
  __shared__ char pool[32768];
  unsigned short (*Ah)[32] = (unsigned short(*)[32])pool;
  unsigned short (*Al)[32] = (unsigned short(*)[32])(pool + 8192);
  unsigned short (*Bh)[32] = (unsigned short(*)[32])(pool + 16384);
  unsigned short (*Bl)[32] = (unsigned short(*)[32])(pool + 24576);
  float (*ep)[34] = (float(*)[34])pool;

  const int tid = threadIdx.x;
  const int lane = tid & 63;
  const int w = tid >> 6;
  const int wr2 = w >> 1, wc2 = w & 1;
  const int p = blockIdx.x;
  const int n0 = blockIdx.y * 128;
  const unsigned short* bhs = (p == 2) ? Mth : Mh;
  const unsigned short* bls = (p == 2) ? Mtl : Ml;
  const int rowoff = (p == 0) ? 0 : 128;
  float* outp = (p == 0) ? J0 : (p == 1) ? J1 : I1;

  float4v acc[4][4];
#pragma unroll
  for (int r = 0; r < 4; ++r)
#pragma unroll
    for (int c = 0; c < 4; ++c) acc[r][c] = (float4v){0.f, 0.f, 0.f, 0.f};

  const int sn = tid >> 1, shalf = tid & 1;
  for (int ch = 0; ch < 4; ++ch) {
    __syncthreads();
    {
      int gn = n0 + sn;
      gn = gn < N ? gn : N - 1;
      STAGE_A_F32(hv + (size_t)gn * 128 + ch * 32 + shalf * 16);
      size_t boff = (size_t)(rowoff + sn) * 512 + ch * 32 + shalf * 16;
      STAGE_B_BF16(bhs + boff, bls + boff);
    }
    __syncthreads();
    MFMA_CHUNK();
  }

  // epilogue: per 32-col group, transpose via LDS, coalesced fp32 store
  for (int g = 0; g < 4; ++g) {
    __syncthreads();
    if (wc2 == (g >> 1)) {
      int ln = lane & 15, kq = lane >> 4;
#pragma unroll
      for (int cc = 0; cc < 2; ++cc) {
        int c = (g & 1) * 2 + cc;
#pragma unroll
        for (int r = 0; r < 4; ++r)
#pragma unroll
          for (int reg = 0; reg < 4; ++reg)
            ep[wr2 * 64 + r * 16 + kq * 4 + reg][cc * 16 + ln] = acc[r][c][reg];
      }
    }
    __syncthreads();
    int row = tid >> 1, half = tid & 1;
    int gn = n0 + row;
    if (gn < N) {
#pragma unroll
      for (int j = 0; j < 4; ++j)
        *(float4*)&outp[(size_t)gn * 128 + 32 * g + 16 * half + 4 * j] =
            *(const float4*)&ep[row][16 * half + 4 * j];
    }
  }
}

// ---------------- K3: per-query vectors w,u,y and scalar c_b ----------------
__global__ __launch_bounds__(128) void k3_query(const float* __restrict__ qsrc,
                                                const float* __restrict__ qrel,
                                                const float* __restrict__ M,
                                                const float* __restrict__ Mt,
                                                float* __restrict__ wv,
                                                float* __restrict__ uv,
                                                float* __restrict__ yv,
                                                float* __restrict__ cb) {
  __shared__ float qcat[256];
  __shared__ float red[128];
  int b = blockIdx.x, d = threadIdx.x;
  qcat[d] = qsrc[b * 128 + d];
  qcat[128 + d] = qrel[b * 128 + d];
  __syncthreads();
  float w = 0.f, u = 0.f, y = 0.f, t1 = 0.f, t2 = 0.f;
  for (int c = 0; c < 256; ++c) {
    float q = qcat[c];
    size_t row = (size_t)(256 + c) * 512;
    w += Mt[row + d] * q;                        // M[d][256+c]
    u += M[row + d] * q;                         // M[256+c][d]
    y += (Mt[row + 128 + d] + M[row + 128 + d]) * q;  // x + v
    t1 += M[row + 256 + d] * q;                  // for c_b, col 256+d
    t2 += M[row + 384 + d] * q;                  // for c_b, col 384+d
  }
  wv[b * 128 + d] = w;
  uv[b * 128 + d] = u;
  yv[b * 128 + d] = y;
  red[d] = qcat[d] * t1 + qcat[128 + d] * t2;
  __syncthreads();
  for (int s = 64; s > 0; s >>= 1) {
    if (d < s) red[d] += red[d + s];
    __syncthreads();
  }
  if (d == 0) cb[b] = red[0];
}

// ---------------- K4m: edge_const via MFMA ----------------
__global__ __launch_bounds__(256) void k4m_mfma(
    const float* __restrict__ rel, const unsigned short* __restrict__ Mth,
    const unsigned short* __restrict__ Mtl, const float* __restrict__ yv,
    const float* __restrict__ cbp, float* __restrict__ ec) {
  __shared__ char pool[32768];
  unsigned short (*Ah)[32] = (unsigned short(*)[32])pool;
  unsigned short (*Al)[32] = (unsigned short(*)[32])(pool + 8192);
  unsigned short (*Bh)[32] = (unsigned short(*)[32])(pool + 16384);
  unsigned short (*Bl)[32] = (unsigned short(*)[32])(pool + 24576);
  float (*ep)[34] = (float(*)[34])pool;

  const int tid = threadIdx.x;
  const int lane = tid & 63;
  const int w = tid >> 6;
  const int wr2 = w >> 1, wc2 = w & 1;
  const int e0 = blockIdx.x * 128;
  const int b = e0 >> EPQ_SHIFT;

  float4v acc[4][4];
#pragma unroll
  for (int r = 0; r < 4; ++r)
#pragma unroll
    for (int c = 0; c < 4; ++c) acc[r][c] = (float4v){0.f, 0.f, 0.f, 0.f};

  const int sn = tid >> 1, shalf = tid & 1;
  for (int ch = 0; ch < 4; ++ch) {
    __syncthreads();
    {
      STAGE_A_F32(rel + (size_t)(e0 + sn) * 128 + ch * 32 + shalf * 16);
      size_t boff = (size_t)(128 + sn) * 512 + 128 + ch * 32 + shalf * 16;
      STAGE_B_BF16(Mth + boff, Mtl + boff);
    }
    __syncthreads();
    MFMA_CHUNK();
  }

  float part = 0.f;
  const int e_loc = tid >> 1, half = tid & 1;
  for (int g = 0; g < 4; ++g) {
    __syncthreads();
    if (wc2 == (g >> 1)) {
      int ln = lane & 15, kq = lane >> 4;
#pragma unroll
      for (int cc = 0; cc < 2; ++cc) {
        int c = (g & 1) * 2 + cc;
#pragma unroll
        for (int r = 0; r < 4; ++r)
#pragma unroll
          for (int reg = 0; reg < 4; ++reg)
            ep[wr2 * 64 + r * 16 + kq * 4 + reg][cc * 16 + ln] = acc[r][c][reg];
      }
    }
    __syncthreads();
    const float* rsrc = rel + (size_t)(e0 + e_loc) * 128 + 32 * g + 16 * half;
    const float* ysrc = yv + b * 128 + 32 * g + 16 * half;
#pragma unroll
    for (int j = 0; j < 4; ++j) {
      float4 q = *(const float4*)&ep[e_loc][16 * half + 4 * j];
      float4 rr = *(const float4*)&rsrc[4 * j];
      float4 yy = *(const float4*)&ysrc[4 * j];
      part += (q.x + yy.x) * rr.x + (q.y + yy.y) * rr.y +
              (q.z + yy.z) * rr.z + (q.w + yy.w) * rr.w;
    }
  }
  part += __shfl_xor(part, 1, 64);
  if ((tid & 1) == 0) ec[e0 + e_loc] = part + cbp[b];
}

// ---------------- K5: per-edge logits + segment max (round-8 form) --------
__global__ __launch_bounds__(256) void k5_logits(const float* __restrict__ rel,
                                                 const float* __restrict__ hv,
                                                 const float* __restrict__ J0,
                                                 const float* __restrict__ J1,
                                                 const float* __restrict__ I1,
                                                 const float* __restrict__ wv,
                                                 const float* __restrict__ uv,
                                                 const float* __restrict__ ec,
                                                 const int* __restrict__ node_i,
                                                 const int* __restrict__ node_j,
                                                 float* __restrict__ logits,
                                                 unsigned* __restrict__ segkey) {
  __shared__ float wl[128];
  __shared__ float ul[128];
  int tid = threadIdx.x;
  int e0 = blockIdx.x * 16;
  int b = e0 >> EPQ_SHIFT;
  if (tid < 128) wl[tid] = wv[b * 128 + tid];
  else ul[tid - 128] = uv[b * 128 + (tid - 128)];
  __syncthreads();
  int lane = tid & 15, eg = tid >> 4;
  int e = e0 + eg;
  int i = node_i[e], j = node_j[e];
  int c0 = lane * 8;

  float rr[8], hi[8], hj[8], a0[8], a1[8], ii[8];
  *(float4*)&rr[0] = *(const float4*)&rel[(size_t)e * 128 + c0];
  *(float4*)&rr[4] = *(const float4*)&rel[(size_t)e * 128 + c0 + 4];
  *(float4*)&hi[0] = *(const float4*)&hv[(size_t)i * 128 + c0];
  *(float4*)&hi[4] = *(const float4*)&hv[(size_t)i * 128 + c0 + 4];
  *(float4*)&hj[0] = *(const float4*)&hv[(size_t)j * 128 + c0];
  *(float4*)&hj[4] = *(const float4*)&hv[(size_t)j * 128 + c0 + 4];
  *(float4*)&a0[0] = *(const float4*)&J0[(size_t)j * 128 + c0];
  *(float4*)&a0[4] = *(const float4*)&J0[(size_t)j * 128 + c0 + 4];
  *(float4*)&a1[0] = *(const float4*)&J1[(size_t)j * 128 + c0];
  *(float4*)&a1[4] = *(const float4*)&J1[(size_t)j * 128 + c0 + 4];
  *(float4*)&ii[0] = *(const float4*)&I1[(size_t)i * 128 + c0];
  *(float4*)&ii[4] = *(const float4*)&I1[(size_t)i * 128 + c0 + 4];

  float p = 0.f;
#pragma unroll
  for (int k = 0; k < 8; ++k) {
    p += hi[k] * a0[k];               // hvi . J0[j]
    p += rr[k] * (a1[k] + ii[k]);     // rel . (J1[j] + I1[i])
    p += hi[k] * wl[c0 + k];          // hvi . w_b
    p += hj[k] * ul[c0 + k];          // hvj . u_b
  }
#pragma unroll
  for (int m = 8; m >= 1; m >>= 1) p += __shfl_xor(p, m, 64);
  if (lane == 0) {
    float lg = p + ec[e];
    logits[e] = lg;
    atomicMax(&segkey[i], enc_f(lg));
  }
}

// ---------------- K6: ex = exp(logit - segmax), segment sum ----------------
__global__ void k6_exp(float* __restrict__ exb, const int* __restrict__ node_i,
                       const unsigned* __restrict__ segkey,
                       float* __restrict__ segsum, int E) {
  int e = blockIdx.x * 256 + threadIdx.x;
  if (e >= E) return;
  int i = node_i[e];
  float m = dec_f(segkey[i]);
  float ex = expf(exb[e] - m);
  exb[e] = ex;
  atomicAdd(&segsum[i], ex);
}

// ---------------- K7: per-query exact top-256 radix select + scatter-add ----
__global__ __launch_bounds__(256) void k7_topk(const float* __restrict__ exb,
                                               const int* __restrict__ node_i,
                                               const int* __restrict__ node_j,
                                               const float* __restrict__ segsum,
                                               const float* __restrict__ score,
                                               float* __restrict__ out) {
  __shared__ unsigned vals[2048];
  __shared__ unsigned hist[256];
  __shared__ unsigned sc[256];
  __shared__ unsigned tie_scan[256];
  __shared__ unsigned sel_info[2];
  int q = blockIdx.x, t = threadIdx.x;
  size_t base = (size_t)q * 2048;
#pragma unroll
  for (int l = 0; l < 8; ++l) {
    int el = t * 8 + l;
    int i = node_i[base + el];
    float tgt = exb[base + el] / segsum[i] * score[i];  // attn * src_score >= 0
    vals[el] = __float_as_uint(tgt);
  }
  __syncthreads();
  unsigned prefix = 0, need = KSEL;
  for (int pass = 3; pass >= 0; --pass) {
    hist[t] = 0;
    __syncthreads();
    int sh = pass * 8;
#pragma unroll
    for (int l = 0; l < 8; ++l) {
      unsigned v = vals[t * 8 + l];
      bool match = (pass == 3) || ((v >> (sh + 8)) == (prefix >> (sh + 8)));
      if (match) atomicAdd(&hist[(v >> sh) & 255u], 1u);
    }
    __syncthreads();
    sc[t] = hist[t];
    __syncthreads();
    for (int off = 1; off < 256; off <<= 1) {  // suffix-inclusive sum
      unsigned add = (t + off < 256) ? sc[t + off] : 0u;
      __syncthreads();
      sc[t] += add;
      __syncthreads();
    }
    unsigned above = sc[t] - hist[t];
    if (above < need && need <= sc[t]) {
      sel_info[0] = (unsigned)t;
      sel_info[1] = need - above;
    }
    __syncthreads();
    prefix |= sel_info[0] << sh;
    need = sel_info[1];
    __syncthreads();
  }
  unsigned T = prefix, r = need;
  unsigned lc = 0;
#pragma unroll
  for (int l = 0; l < 8; ++l)
    if (vals[t * 8 + l] == T) lc++;
  tie_scan[t] = lc;
  __syncthreads();
  unsigned own = lc;
  for (int off = 1; off < 256; off <<= 1) {
    unsigned add = (t >= off) ? tie_scan[t - off] : 0u;
    __syncthreads();
    tie_scan[t] += add;
    __syncthreads();
  }
  unsigned excl = tie_scan[t] - own;
  unsigned cnt = 0;
#pragma unroll
  for (int l = 0; l < 8; ++l) {
    int el = t * 8 + l;
    unsigned v = vals[el];
    bool take = false;
    if (v > T) take = true;
    else if (v == T) { if (excl + cnt < r) take = true; cnt++; }
    if (take) {
      int j = node_j[base + el];
      atomicAdd(&out[j], __uint_as_float(v));
    }
  }
}

// ---------------- host ----------------
extern "C" void kernel_launch(void* const* d_in, const int* in_sizes, int n_in,
                              void* d_out, int out_size, void* d_ws, size_t ws_size,
                              hipStream_t stream) {
  const float* score = (const float*)d_in[0];
  const float* hv    = (const float*)d_in[1];
  const float* rel   = (const float*)d_in[2];
  const float* qsrc  = (const float*)d_in[3];
  const float* qrel  = (const float*)d_in[4];
  const float* Wq    = (const float*)d_in[5];
  const float* Wk    = (const float*)d_in[6];
  const int* node_i  = (const int*)d_in[8];
  const int* node_j  = (const int*)d_in[9];

  const int N = in_sizes[0];            // 50000
  const int B = in_sizes[3] / 128;      // 64
  const int E = in_sizes[2] / 128;      // 131072

  float* ws = (float*)d_ws;
  float* M  = ws;
  float* Mt = M + 262144;
  float* J0 = Mt + 262144;
  float* J1 = J0 + (size_t)N * 128;
  float* I1 = J1 + (size_t)N * 128;
  float* wv = I1 + (size_t)N * 128;
  float* uv = wv + (size_t)B * 128;
  float* yv = uv + (size_t)B * 128;
  float* cb = yv + (size_t)B * 128;
  float* ec = cb + B;
  float* exb = ec + E;
  unsigned* segkey = (unsigned*)(exb + E);
  float* segsum = (float*)(segkey + N);
  unsigned short* Mh  = (unsigned short*)(segsum + N);
  unsigned short* Ml  = Mh + 262144;
  unsigned short* Mth = Ml + 262144;
  unsigned short* Mtl = Mth + 262144;
  float* out = (float*)d_out;

  k0_init<<<(N + 255) / 256, 256, 0, stream>>>(out, segsum, segkey, N);
  k1_gemmM<<<dim3(8, 8), 256, 0, stream>>>(Wq, Wk, M, Mt, Mh, Ml, Mth, Mtl);
  k2m_mfma<<<dim3(3, (N + 127) / 128), 256, 0, stream>>>(hv, Mh, Ml, Mth, Mtl,
                                                         J0, J1, I1, N);
  k3_query<<<B, 128, 0, stream>>>(qsrc, qrel, M, Mt, wv, uv, yv, cb);
  k4m_mfma<<<E / 128, 256, 0, stream>>>(rel, Mth, Mtl, yv, cb, ec);
  k5_logits<<<E / 16, 256, 0, stream>>>(rel, hv, J0, J1, I1, wv, uv, ec,
                                        node_i, node_j, exb, segkey);
  k6_exp<<<(E + 255) / 256, 256, 0, stream>>>(exb, node_i, segkey, segsum, E);
  k7_topk<<<B, 256, 0, stream>>>(exb, node_i, node_j, segsum, score, out);
}